// Round 8
// baseline (125.820 us; speedup 1.0000x reference)
//
#include <hip/hip_runtime.h>
#include <stdint.h>

#define K_DIM 1024
#define N_DIM 1024
#define BM 256
#define BN3 128
#define BK 64
#define NK (K_DIM / BK)  // 16
#define UNIT_U32 ((BM + BN3) * 32)  // 48 KB per ring unit

typedef __attribute__((ext_vector_type(4))) float f32x4;
typedef __attribute__((ext_vector_type(8))) short bf16x8;
typedef __attribute__((ext_vector_type(4))) uint32_t u32x4;

// round-half-up to bf16, pack two: low 16 = a, high 16 = b
__device__ __forceinline__ uint32_t pack_bf16(float a, float b) {
  uint32_t ua = __builtin_bit_cast(uint32_t, a) + 0x8000u;
  uint32_t ub = __builtin_bit_cast(uint32_t, b) + 0x8000u;
  return __builtin_amdgcn_perm(ub, ua, 0x07060302u);
}

__device__ __forceinline__ float wbin1(float v, float kkv, float aav) {
  float t = v * kkv;
  t = fminf(fmaxf(t, -1.0f), 1.0f);
  return t * aav;
}

// ---------------- kernel 1: w_bin = bf16(aa*clamp(kk*w,-1,1)) into ws ------
__global__ __launch_bounds__(256) void wconv(const float* __restrict__ w,
                                             const float* __restrict__ kkp,
                                             const float* __restrict__ aap,
                                             uint32_t* __restrict__ wb) {
  const float kkv = kkp[0];
  const float aav = aap[0];
  const int g = blockIdx.x * 256 + threadIdx.x;  // 16 floats per thread
  const f32x4* src = (const f32x4*)(w + (size_t)g * 16);
  f32x4 v0 = src[0], v1 = src[1], v2 = src[2], v3 = src[3];
  uint32_t p[8];
#pragma unroll
  for (int i = 0; i < 4; ++i) {
    f32x4 v = i == 0 ? v0 : (i == 1 ? v1 : (i == 2 ? v2 : v3));
    p[2 * i] = pack_bf16(wbin1(v[0], kkv, aav), wbin1(v[1], kkv, aav));
    p[2 * i + 1] = pack_bf16(wbin1(v[2], kkv, aav), wbin1(v[3], kkv, aav));
  }
  u32x4* dst = (u32x4*)(wb + (size_t)g * 8);
  dst[0] = u32x4{p[0], p[1], p[2], p[3]};
  dst[1] = u32x4{p[4], p[5], p[6], p[7]};
}

// ---------------- kernel 2: x fp32 -> bf16 (packed) into ws ----------------
__global__ __launch_bounds__(256) void xconv(const float* __restrict__ x,
                                             uint32_t* __restrict__ xb) {
  const size_t g = (size_t)blockIdx.x * 256 + threadIdx.x;  // 16 floats
  const f32x4* src = (const f32x4*)(x + g * 16);
  f32x4 v0 = src[0], v1 = src[1], v2 = src[2], v3 = src[3];
  uint32_t p[8];
  p[0] = pack_bf16(v0[0], v0[1]); p[1] = pack_bf16(v0[2], v0[3]);
  p[2] = pack_bf16(v1[0], v1[1]); p[3] = pack_bf16(v1[2], v1[3]);
  p[4] = pack_bf16(v2[0], v2[1]); p[5] = pack_bf16(v2[2], v2[3]);
  p[6] = pack_bf16(v3[0], v3[1]); p[7] = pack_bf16(v3[2], v3[3]);
  u32x4* dst = (u32x4*)(xb + g * 8);
  dst[0] = u32x4{p[0], p[1], p[2], p[3]};
  dst[1] = u32x4{p[4], p[5], p[6], p[7]};
}

// ---------------- kernel 3 (fast): 3-ring counted-vmcnt GEMM ---------------
// 256x128 tile, 512 thr = 8 waves (4 wave-rows x 2 wave-cols), wave 64x64
// out = 4x4 frags, BK=64. LDS ring of 3 units (A[256][64]+B[128][64] bf16 =
// 48 KB each, 144 KB total). Stage unit t+2 during tile t (6 gload_lds/wave,
// wave-uniform issue order); boundary wait vmcnt(6) retires t+1 only — vmcnt
// never 0 in steady state, each unit gets ~2 tiles of MFMA cover. 2 phases
// per tile x 16 MFMA. Row = 32 u32 = 8 slots x 16B, phys_slot = slot^(row&7)
// (source pre-swizzled for DMA, same XOR on reads).
__global__ __launch_bounds__(512, 2) void binlin_gemm3r(
    const uint32_t* __restrict__ xb, const uint32_t* __restrict__ wb,
    const float* __restrict__ bias, float* __restrict__ out) {
  __shared__ uint32_t lds[3 * UNIT_U32];  // 144 KB

  const int tid = threadIdx.x;

  // bijective XCD swizzle (grid=1024): 8 n-blocks of an m-panel -> same L2
  const int per = gridDim.x >> 3;
  const int logical = (blockIdx.x & 7) * per + (blockIdx.x >> 3);
  const int mIdx = logical >> 3;  // N_DIM/BN3 = 8
  const int nIdx = logical & 7;
  const int row0 = mIdx * BM;
  const int col0 = nIdx * BN3;

  const int w8 = tid >> 6;
  const int lane = tid & 63;
  const int brow = lane >> 3;
  const int bslot = (lane & 7) ^ brow;  // pre-swizzled source slot
  // A: wave w8 stages rows w8*32 .. +32 (4 ops x 8 rows)
  const uint32_t* ga_base =
      xb + (size_t)(row0 + w8 * 32 + brow) * (K_DIM / 2) + bslot * 4;
  // B: wave w8 stages rows w8*16 .. +16 (2 ops x 8 rows)
  const uint32_t* gb_base =
      wb + (size_t)(col0 + w8 * 16 + brow) * (K_DIM / 2) + bslot * 4;

  const int wr = w8 >> 1;  // 0..3 (m)
  const int wc = w8 & 1;   // 0..1 (n)
  const int cl = lane & 15;
  const int kg = lane >> 4;

  f32x4 acc[4][4] = {};
  bf16x8 af[2][4], bfr[2][2];

  // stage A-ops {c,c+1} of tile kt into unit SD
#define STAGE_A2(kt, SD, c0)                                              \
  do {                                                                    \
    _Pragma("unroll") for (int c = (c0); c < (c0) + 2; ++c) {             \
      __builtin_amdgcn_global_load_lds(                                   \
          (const __attribute__((address_space(1))) uint32_t*)(            \
              ga_base + (size_t)(c * 8) * (K_DIM / 2) + (kt) * 32),       \
          (__attribute__((address_space(3))) uint32_t*)(                  \
              (SD) + (w8 * 32 + c * 8) * 32),                             \
          16, 0, 0);                                                      \
    }                                                                     \
  } while (0)

#define STAGE_B1(kt, SD, c)                                               \
  do {                                                                    \
    __builtin_amdgcn_global_load_lds(                                     \
        (const __attribute__((address_space(1))) uint32_t*)(              \
            gb_base + (size_t)((c) * 8) * (K_DIM / 2) + (kt) * 32),       \
        (__attribute__((address_space(3))) uint32_t*)(                    \
            (SD) + BM * 32 + (w8 * 16 + (c) * 8) * 32),                   \
        16, 0, 0);                                                        \
  } while (0)

#define READ_AF(AB)                                                            \
  _Pragma("unroll") for (int ks = 0; ks < 2; ++ks)                             \
  _Pragma("unroll") for (int m = 0; m < 4; ++m) {                              \
    int rr = wr * 64 + m * 16 + cl;                                            \
    af[ks][m] =                                                                \
        *(const bf16x8*)((AB) + rr * 32 + (((ks * 4 + kg) ^ (rr & 7)) * 4));   \
  }

#define READ_BF(BB, NH)                                                        \
  _Pragma("unroll") for (int ks = 0; ks < 2; ++ks)                             \
  _Pragma("unroll") for (int n = 0; n < 2; ++n) {                              \
    int rr = wc * 64 + ((NH)*2 + n) * 16 + cl;                                 \
    bfr[ks][n] =                                                               \
        *(const bf16x8*)((BB) + rr * 32 + (((ks * 4 + kg) ^ (rr & 7)) * 4));   \
  }

#define PHTAIL(NH)                                                             \
  __builtin_amdgcn_s_barrier();                                                \
  asm volatile("s_waitcnt lgkmcnt(0)" ::: "memory");                           \
  __builtin_amdgcn_sched_barrier(0);                                           \
  __builtin_amdgcn_s_setprio(1);                                               \
  _Pragma("unroll") for (int ks = 0; ks < 2; ++ks)                             \
  _Pragma("unroll") for (int m = 0; m < 4; ++m)                                \
  _Pragma("unroll") for (int n = 0; n < 2; ++n)                                \
  acc[m][(NH)*2 + n] = __builtin_amdgcn_mfma_f32_16x16x32_bf16(                \
      af[ks][m], bfr[ks][n], acc[m][(NH)*2 + n], 0, 0, 0);                     \
  __builtin_amdgcn_s_setprio(0);

  // prologue: stage units 0 and 1 fully (issue order = unit order), then
  // retire unit 0 only (vmcnt(6) leaves unit 1 in flight)
  STAGE_A2(0, &lds[0], 0);
  STAGE_A2(0, &lds[0], 2);
  STAGE_B1(0, &lds[0], 0);
  STAGE_B1(0, &lds[0], 1);
  STAGE_A2(1, &lds[UNIT_U32], 0);
  STAGE_A2(1, &lds[UNIT_U32], 2);
  STAGE_B1(1, &lds[UNIT_U32], 0);
  STAGE_B1(1, &lds[UNIT_U32], 1);
  asm volatile("s_waitcnt vmcnt(6)" ::: "memory");
  __builtin_amdgcn_s_barrier();

  int cu = 0, su = 2;  // compute slot = t%3, stage slot = (t+2)%3
  for (int t = 0; t < NK; ++t) {
    const uint32_t* AB = &lds[cu * UNIT_U32];
    const uint32_t* BB = AB + BM * 32;
    uint32_t* SD = &lds[su * UNIT_U32];
    const bool more = (t + 2) < NK;
    // ph0: quad n0-1 — stage first half of unit t+2
    READ_AF(AB);
    READ_BF(BB, 0);
    if (more) {
      STAGE_A2(t + 2, SD, 0);
      STAGE_B1(t + 2, SD, 0);
    }
    PHTAIL(0);
    __builtin_amdgcn_s_barrier();
    // ph1: quad n2-3 — stage second half of unit t+2
    READ_BF(BB, 1);
    if (more) {
      STAGE_A2(t + 2, SD, 2);
      STAGE_B1(t + 2, SD, 1);
    }
    PHTAIL(1);
    // boundary: retire unit t+1 only; unit t+2 stays in flight
    if (t < NK - 2) {
      asm volatile("s_waitcnt vmcnt(6)" ::: "memory");
    } else if (t == NK - 2) {
      asm volatile("s_waitcnt vmcnt(0)" ::: "memory");
    }
    __builtin_amdgcn_s_barrier();
    cu = (cu == 2) ? 0 : cu + 1;
    su = (su == 2) ? 0 : su + 1;
  }

  // epilogue: bias + fp32 store
#pragma unroll
  for (int n = 0; n < 4; ++n) {
    int col = col0 + wc * 64 + n * 16 + cl;
    float bv = bias[col];
#pragma unroll
    for (int m = 0; m < 4; ++m) {
      int rowb = row0 + wr * 64 + m * 16 + kg * 4;
#pragma unroll
      for (int i = 0; i < 4; ++i) {
        out[(size_t)(rowb + i) * N_DIM + col] = acc[m][n][i] + bv;
      }
    }
  }
#undef STAGE_A2
#undef STAGE_B1
#undef READ_AF
#undef READ_BF
#undef PHTAIL
}

// ---------------- fallback GEMM (R5 fb, used when ws too small) ------------
#define BNF 256
__global__ __launch_bounds__(512, 2) void binlin_gemm_fb(
    const float* __restrict__ x, const uint32_t* __restrict__ wb,
    const float* __restrict__ bias, float* __restrict__ out) {
  __shared__ uint32_t lds[2][(BM + BNF) * 32];

  const int tid = threadIdx.x;
  const int per = gridDim.x >> 3;
  const int logical = (blockIdx.x & 7) * per + (blockIdx.x >> 3);
  const int mIdx = logical >> 2;
  const int nIdx = logical & 3;
  const int row0 = mIdx * BM;
  const int col0 = nIdx * BNF;

  const int r = tid >> 1;
  const int h = tid & 1;
  const int sw = r & 7;
  const float* ga = x + (size_t)(row0 + r) * K_DIM + h * 32;
  const int aoff = r * 32;

  const int w8 = tid >> 6;
  const int lane = tid & 63;
  const int brow = lane >> 3;
  const int bslot = (lane & 7) ^ brow;
  const uint32_t* gb_base =
      wb + (size_t)(col0 + w8 * 32 + brow) * (K_DIM / 2) + bslot * 4;
  const int boff = (w8 * 32) * 32;

  const int wr = w8 >> 2;
  const int wc = w8 & 3;
  const int cl = lane & 15;
  const int kg = lane >> 4;

  f32x4 acc[8][4] = {};
  f32x4 ra[8];

#define LOADA(kt)                                                \
  {                                                              \
    const f32x4* pa = (const f32x4*)(ga + (kt)*BK);              \
    _Pragma("unroll") for (int i = 0; i < 8; ++i) ra[i] = pa[i]; \
  }
#define WRITEA(buf)                                                       \
  {                                                                       \
    uint32_t* lap = &lds[buf][0] + aoff;                                  \
    _Pragma("unroll") for (int j = 0; j < 4; ++j) {                       \
      u32x4 pk = {pack_bf16(ra[2 * j][0], ra[2 * j][1]),                  \
                  pack_bf16(ra[2 * j][2], ra[2 * j][3]),                  \
                  pack_bf16(ra[2 * j + 1][0], ra[2 * j + 1][1]),          \
                  pack_bf16(ra[2 * j + 1][2], ra[2 * j + 1][3])};         \
      *(u32x4*)(lap + (((h * 4 + j) ^ sw) * 4)) = pk;                     \
    }                                                                     \
  }
#define STAGEB(kt, buf)                                                    \
  {                                                                        \
    uint32_t* lbp = &lds[buf][BM * 32] + boff;                             \
    _Pragma("unroll") for (int c = 0; c < 4; ++c) {                        \
      __builtin_amdgcn_global_load_lds(                                    \
          (const __attribute__((address_space(1))) uint32_t*)(             \
              gb_base + (size_t)(c * 8) * (K_DIM / 2) + (kt)*32),          \
          (__attribute__((address_space(3))) uint32_t*)(lbp + c * 8 * 32), \
          16, 0, 0);                                                       \
    }                                                                      \
  }
#define COMPUTE(buf)                                                           \
  {                                                                            \
    const uint32_t* A = &lds[buf][0];                                          \
    const uint32_t* B = &lds[buf][BM * 32];                                    \
    _Pragma("unroll") for (int ks = 0; ks < 2; ++ks) {                         \
      bf16x8 bfr[4];                                                           \
      _Pragma("unroll") for (int n = 0; n < 4; ++n) {                          \
        int rr = wc * 64 + n * 16 + cl;                                        \
        bfr[n] =                                                               \
            *(const bf16x8*)(B + rr * 32 + (((ks * 4 + kg) ^ (rr & 7)) * 4));  \
      }                                                                        \
      _Pragma("unroll") for (int mh = 0; mh < 2; ++mh) {                       \
        bf16x8 af[4];                                                          \
        _Pragma("unroll") for (int m = 0; m < 4; ++m) {                        \
          int rr = wr * 128 + (mh * 4 + m) * 16 + cl;                          \
          af[m] =                                                              \
              *(const bf16x8*)(A + rr * 32 + (((ks * 4 + kg) ^ (rr & 7)) * 4));\
        }                                                                      \
        __builtin_amdgcn_s_setprio(1);                                         \
        _Pragma("unroll") for (int m = 0; m < 4; ++m)                          \
            _Pragma("unroll") for (int n = 0; n < 4; ++n)                      \
                acc[mh * 4 + m][n] = __builtin_amdgcn_mfma_f32_16x16x32_bf16(  \
                    af[m], bfr[n], acc[mh * 4 + m][n], 0, 0, 0);               \
        __builtin_amdgcn_s_setprio(0);                                         \
      }                                                                        \
    }                                                                          \
  }

  LOADA(0);
  STAGEB(0, 0);
  WRITEA(0);
  asm volatile("s_waitcnt vmcnt(0) lgkmcnt(0)" ::: "memory");
  __builtin_amdgcn_s_barrier();

  for (int kt2 = 0; kt2 < NK; kt2 += 2) {
    LOADA(kt2 + 1);
    STAGEB(kt2 + 1, 1);
    asm volatile("s_waitcnt vmcnt(12)" ::: "memory");
    __builtin_amdgcn_s_barrier();
    __builtin_amdgcn_sched_barrier(0);
    COMPUTE(0);
    WRITEA(1);
    asm volatile("s_waitcnt lgkmcnt(0)" ::: "memory");
    if (kt2 + 2 < NK) {
      LOADA(kt2 + 2);
      STAGEB(kt2 + 2, 0);
      asm volatile("s_waitcnt vmcnt(12)" ::: "memory");
    } else {
      asm volatile("s_waitcnt vmcnt(0)" ::: "memory");
    }
    __builtin_amdgcn_s_barrier();
    __builtin_amdgcn_sched_barrier(0);
    COMPUTE(1);
    if (kt2 + 2 < NK) {
      WRITEA(0);
      asm volatile("s_waitcnt lgkmcnt(0)" ::: "memory");
    }
  }

#pragma unroll
  for (int n = 0; n < 4; ++n) {
    int col = col0 + wc * 64 + n * 16 + cl;
    float bv = bias[col];
#pragma unroll
    for (int m = 0; m < 8; ++m) {
      int rowb = row0 + wr * 128 + m * 16 + kg * 4;
#pragma unroll
      for (int i = 0; i < 4; ++i) {
        out[(size_t)(rowb + i) * N_DIM + col] = acc[m][n][i] + bv;
      }
    }
  }
#undef LOADA
#undef WRITEA
#undef STAGEB
#undef COMPUTE
}

extern "C" void kernel_launch(void* const* d_in, const int* in_sizes, int n_in,
                              void* d_out, int out_size, void* d_ws, size_t ws_size,
                              hipStream_t stream) {
  const float* x = (const float*)d_in[0];
  const float* w = (const float*)d_in[1];
  const float* bias = (const float*)d_in[2];
  const float* kk = (const float*)d_in[3];
  const float* aa = (const float*)d_in[4];
  float* out = (float*)d_out;

  uint32_t* wb = (uint32_t*)d_ws;  // 2 MB bf16 w_bin at offset 0
  wconv<<<(N_DIM * K_DIM) / (256 * 16), 256, 0, stream>>>(w, kk, aa, wb);

  const int M = in_sizes[0] / K_DIM;  // 32768

  const size_t wb_bytes = (size_t)N_DIM * K_DIM * 2;  // 2 MB
  const size_t xb_bytes = (size_t)M * K_DIM * 2;      // 64 MB
  if (ws_size >= wb_bytes + xb_bytes) {
    uint32_t* xbp = (uint32_t*)((char*)d_ws + wb_bytes);
    xconv<<<(int)(((size_t)M * K_DIM) / (256 * 16)), 256, 0, stream>>>(x, xbp);
    const int grid = (M / BM) * (N_DIM / BN3);  // 128 * 8 = 1024
    binlin_gemm3r<<<grid, 512, 0, stream>>>(xbp, wb, bias, out);
  } else {
    const int grid = (M / BM) * (N_DIM / BNF);  // 512
    binlin_gemm_fb<<<grid, 512, 0, stream>>>(x, wb, bias, out);
  }
}